// Round 1
// baseline (394.337 us; speedup 1.0000x reference)
//
#include <hip/hip_runtime.h>
#include <hip/hip_bf16.h>
#include <math.h>

#define NNODES 50000
#define NF 128
#define NEDGES 800000
#define ALPHA 0.2f
#define EPS 1e-16f

// ---------------------------------------------------------------------------
// K1: Wh = h @ W   (50000x128 @ 128x128, f32)
// 64 rows per block, 256 threads. h rows staged in LDS; W read from L2.
// Each thread computes an 8-row x 4-col strip with float4 accumulators.
// ---------------------------------------------------------------------------
__global__ __launch_bounds__(256) void gemm_wh(const float* __restrict__ h,
                                               const float* __restrict__ W,
                                               float* __restrict__ Wh) {
    __shared__ float hs[64][128];
    const int tid = threadIdx.x;
    const int row0 = blockIdx.x * 64;

    // cooperative load of 64 h-rows (8192 floats), coalesced
    #pragma unroll
    for (int i = 0; i < 32; ++i) {
        int idx = tid + i * 256;
        int r = idx >> 7, c = idx & 127;
        int gr = row0 + r;
        hs[r][c] = (gr < NNODES) ? h[gr * NF + c] : 0.f;
    }
    __syncthreads();

    const int c4 = (tid & 31) * 4;      // output columns c4..c4+3
    const int rg = (tid >> 5) * 8;      // first of 8 rows

    float4 acc[8];
    #pragma unroll
    for (int r = 0; r < 8; ++r) acc[r] = make_float4(0.f, 0.f, 0.f, 0.f);

    for (int k = 0; k < 128; k += 4) {
        float4 w0 = *(const float4*)&W[(k + 0) * NF + c4];
        float4 w1 = *(const float4*)&W[(k + 1) * NF + c4];
        float4 w2 = *(const float4*)&W[(k + 2) * NF + c4];
        float4 w3 = *(const float4*)&W[(k + 3) * NF + c4];
        #pragma unroll
        for (int r = 0; r < 8; ++r) {
            float4 hv = *(const float4*)&hs[rg + r][k];
            acc[r].x += hv.x * w0.x + hv.y * w1.x + hv.z * w2.x + hv.w * w3.x;
            acc[r].y += hv.x * w0.y + hv.y * w1.y + hv.z * w2.y + hv.w * w3.y;
            acc[r].z += hv.x * w0.z + hv.y * w1.z + hv.z * w2.z + hv.w * w3.z;
            acc[r].w += hv.x * w0.w + hv.y * w1.w + hv.z * w2.w + hv.w * w3.w;
        }
    }

    #pragma unroll
    for (int r = 0; r < 8; ++r) {
        int gr = row0 + rg + r;
        if (gr < NNODES) *(float4*)&Wh[gr * NF + c4] = acc[r];
    }
}

// ---------------------------------------------------------------------------
// K1b: s1 = Wh @ a1, s2 = Wh @ a2 (one wave per row)
// ---------------------------------------------------------------------------
__global__ __launch_bounds__(256) void s12_kernel(const float* __restrict__ Wh,
                                                  const float* __restrict__ a,
                                                  float* __restrict__ s1,
                                                  float* __restrict__ s2) {
    const int wid = threadIdx.x >> 6;
    const int lane = threadIdx.x & 63;
    const int row = blockIdx.x * 4 + wid;
    if (row >= NNODES) return;
    float w0 = Wh[row * NF + lane];
    float w1 = Wh[row * NF + 64 + lane];
    float v1 = w0 * a[lane] + w1 * a[64 + lane];
    float v2 = w0 * a[128 + lane] + w1 * a[192 + lane];
    #pragma unroll
    for (int off = 32; off; off >>= 1) {
        v1 += __shfl_xor(v1, off);
        v2 += __shfl_xor(v2, off);
    }
    if (lane == 0) { s1[row] = v1; s2[row] = v2; }
}

// ---------------------------------------------------------------------------
// K2: per-edge e = leaky_relu(s1[row]+s2[col]); rowsum += e; count[row]++
// ---------------------------------------------------------------------------
__global__ void edge_phase1(const int* __restrict__ ei,
                            const float* __restrict__ s1,
                            const float* __restrict__ s2,
                            float* __restrict__ e,
                            float* __restrict__ rowsum,
                            int* __restrict__ count) {
    int i = blockIdx.x * blockDim.x + threadIdx.x;
    if (i >= NEDGES) return;
    int r = ei[i];
    int c = ei[NEDGES + i];
    float s = s1[r] + s2[c];
    float ev = (s >= 0.f) ? s : ALPHA * s;
    e[i] = ev;
    atomicAdd(&rowsum[r], ev);
    atomicAdd(&count[r], 1);
}

// ---------------------------------------------------------------------------
// K3: single-block exclusive scan of count[] -> rowstart[], cursor[]
// 1024 threads, 49 sequential elements each.
// ---------------------------------------------------------------------------
#define SCAN_ITEMS 49
__global__ __launch_bounds__(1024) void scan_kernel(const int* __restrict__ count,
                                                    int* __restrict__ rowstart,
                                                    int* __restrict__ cursor) {
    __shared__ int sums[1024];
    const int t = threadIdx.x;
    const int base = t * SCAN_ITEMS;
    int s = 0;
    for (int i = 0; i < SCAN_ITEMS; ++i) {
        int idx = base + i;
        if (idx < NNODES) s += count[idx];
    }
    sums[t] = s;
    __syncthreads();
    // inclusive Hillis-Steele scan
    for (int off = 1; off < 1024; off <<= 1) {
        int v = (t >= off) ? sums[t - off] : 0;
        __syncthreads();
        sums[t] += v;
        __syncthreads();
    }
    int running = sums[t] - s;   // exclusive prefix
    for (int i = 0; i < SCAN_ITEMS; ++i) {
        int idx = base + i;
        if (idx < NNODES) {
            rowstart[idx] = running;
            cursor[idx] = running;
            running += count[idx];
        }
    }
    if (t == 1023) rowstart[NNODES] = sums[1023];
}

// ---------------------------------------------------------------------------
// K4: scatter edges into CSR order; store e_exp = exp(e - rowsum[row]) and col
// ---------------------------------------------------------------------------
__global__ void scatter_kernel(const int* __restrict__ ei,
                               const float* __restrict__ e,
                               const float* __restrict__ rowsum,
                               int* __restrict__ cursor,
                               float* __restrict__ sEexp,
                               int* __restrict__ sCol) {
    int i = blockIdx.x * blockDim.x + threadIdx.x;
    if (i >= NEDGES) return;
    int r = ei[i];
    int c = ei[NEDGES + i];
    int pos = atomicAdd(&cursor[r], 1);
    sEexp[pos] = expf(e[i] - rowsum[r]);
    sCol[pos] = c;
}

// ---------------------------------------------------------------------------
// K5: per-row aggregation. One wave per row:
//   denom = sum(e_exp) + EPS;  out[row] = sum (e_exp/denom) * Wh[col]
// ---------------------------------------------------------------------------
__global__ __launch_bounds__(256) void aggregate(const int* __restrict__ rowstart,
                                                 const float* __restrict__ sEexp,
                                                 const int* __restrict__ sCol,
                                                 const float* __restrict__ Wh,
                                                 float* __restrict__ out) {
    const int wid = threadIdx.x >> 6;
    const int lane = threadIdx.x & 63;
    const int row = blockIdx.x * 4 + wid;
    if (row >= NNODES) return;
    const int start = rowstart[row];
    const int end = rowstart[row + 1];

    float ssum = 0.f;
    for (int j = start + lane; j < end; j += 64) ssum += sEexp[j];
    #pragma unroll
    for (int off = 32; off; off >>= 1) ssum += __shfl_xor(ssum, off);
    const float invd = 1.0f / (ssum + EPS);

    float acc0 = 0.f, acc1 = 0.f;
    for (int j = start; j < end; ++j) {
        float w = sEexp[j] * invd;
        int c = sCol[j];
        const float* wh = Wh + (long)c * NF;
        acc0 += w * wh[lane];
        acc1 += w * wh[64 + lane];
    }
    out[row * NF + lane] = acc0;
    out[row * NF + 64 + lane] = acc1;
}

// ---------------------------------------------------------------------------
extern "C" void kernel_launch(void* const* d_in, const int* in_sizes, int n_in,
                              void* d_out, int out_size, void* d_ws, size_t ws_size,
                              hipStream_t stream) {
    const float* h  = (const float*)d_in[0];
    const int*   ei = (const int*)d_in[1];
    const float* W  = (const float*)d_in[2];
    const float* a  = (const float*)d_in[3];
    float* out = (float*)d_out;

    char* ws = (char*)d_ws;
    size_t off = 0;
    auto alloc = [&](size_t bytes) -> void* {
        void* p = ws + off;
        off += (bytes + 255) & ~(size_t)255;
        return p;
    };

    float* Wh      = (float*)alloc((size_t)NNODES * NF * 4);
    float* rowsum  = (float*)alloc((size_t)NNODES * 4);
    int*   count   = (int*)alloc((size_t)NNODES * 4);
    float* s1      = (float*)alloc((size_t)NNODES * 4);
    float* s2      = (float*)alloc((size_t)NNODES * 4);
    int*   rowstart= (int*)alloc((size_t)(NNODES + 1) * 4);
    int*   cursor  = (int*)alloc((size_t)NNODES * 4);
    float* e       = (float*)alloc((size_t)NEDGES * 4);
    float* sEexp   = (float*)alloc((size_t)NEDGES * 4);
    int*   sCol    = (int*)alloc((size_t)NEDGES * 4);

    // zero rowsum + count (contiguous in layout, but memset separately for clarity)
    hipMemsetAsync(rowsum, 0, (size_t)NNODES * 4, stream);
    hipMemsetAsync(count, 0, (size_t)NNODES * 4, stream);

    // K1: GEMM
    gemm_wh<<<(NNODES + 63) / 64, 256, 0, stream>>>(h, W, Wh);
    // K1b: s1/s2
    s12_kernel<<<(NNODES + 3) / 4, 256, 0, stream>>>(Wh, a, s1, s2);
    // K2: per-edge scores + histogram + rowsum
    edge_phase1<<<(NEDGES + 255) / 256, 256, 0, stream>>>(ei, s1, s2, e, rowsum, count);
    // K3: scan
    scan_kernel<<<1, 1024, 0, stream>>>(count, rowstart, cursor);
    // K4: scatter into CSR order with e_exp
    scatter_kernel<<<(NEDGES + 255) / 256, 256, 0, stream>>>(ei, e, rowsum, cursor, sEexp, sCol);
    // K5: aggregate
    aggregate<<<(NNODES + 3) / 4, 256, 0, stream>>>(rowstart, sEexp, sCol, Wh, out);
}

// Round 2
// 284.270 us; speedup vs baseline: 1.3872x; 1.3872x over previous
//
#include <hip/hip_runtime.h>
#include <hip/hip_bf16.h>
#include <math.h>

#define NNODES 50000
#define NF 128
#define NEDGES 800000
#define ALPHA 0.2f
#define EPS 1e-16f
#define NBLK 196            // ceil(50000/256) chunks for the hierarchical scan

// ---------------------------------------------------------------------------
// K1: Wh = h @ W  (50000x128 @ 128x128, f32)  + fused s1/s2 epilogue
// 64 rows per block, 256 threads. Each thread: 8-row x 4-col strip.
// Epilogue: the 32 threads sharing a row-group shfl-reduce s1/s2 per row.
// ---------------------------------------------------------------------------
__global__ __launch_bounds__(256) void gemm_wh(const float* __restrict__ h,
                                               const float* __restrict__ W,
                                               const float* __restrict__ a,
                                               float* __restrict__ Wh,
                                               float* __restrict__ s1,
                                               float* __restrict__ s2) {
    __shared__ float hs[64][128];
    const int tid = threadIdx.x;
    const int row0 = blockIdx.x * 64;

    #pragma unroll
    for (int i = 0; i < 32; ++i) {
        int idx = tid + i * 256;
        int r = idx >> 7, c = idx & 127;
        int gr = row0 + r;
        hs[r][c] = (gr < NNODES) ? h[gr * NF + c] : 0.f;
    }
    __syncthreads();

    const int c4 = (tid & 31) * 4;      // output columns c4..c4+3
    const int rg = (tid >> 5) * 8;      // first of 8 rows

    float4 acc[8];
    #pragma unroll
    for (int r = 0; r < 8; ++r) acc[r] = make_float4(0.f, 0.f, 0.f, 0.f);

    for (int k = 0; k < 128; k += 4) {
        float4 w0 = *(const float4*)&W[(k + 0) * NF + c4];
        float4 w1 = *(const float4*)&W[(k + 1) * NF + c4];
        float4 w2 = *(const float4*)&W[(k + 2) * NF + c4];
        float4 w3 = *(const float4*)&W[(k + 3) * NF + c4];
        #pragma unroll
        for (int r = 0; r < 8; ++r) {
            float4 hv = *(const float4*)&hs[rg + r][k];
            acc[r].x += hv.x * w0.x + hv.y * w1.x + hv.z * w2.x + hv.w * w3.x;
            acc[r].y += hv.x * w0.y + hv.y * w1.y + hv.z * w2.y + hv.w * w3.y;
            acc[r].z += hv.x * w0.z + hv.y * w1.z + hv.z * w2.z + hv.w * w3.z;
            acc[r].w += hv.x * w0.w + hv.y * w1.w + hv.z * w2.w + hv.w * w3.w;
        }
    }

    #pragma unroll
    for (int r = 0; r < 8; ++r) {
        int gr = row0 + rg + r;
        if (gr < NNODES) *(float4*)&Wh[gr * NF + c4] = acc[r];
    }

    // fused s1/s2: per-row dot with a1 (a[0:128]) and a2 (a[128:256])
    float4 a1 = *(const float4*)&a[c4];
    float4 a2 = *(const float4*)&a[128 + c4];
    #pragma unroll
    for (int r = 0; r < 8; ++r) {
        float p1 = acc[r].x * a1.x + acc[r].y * a1.y + acc[r].z * a1.z + acc[r].w * a1.w;
        float p2 = acc[r].x * a2.x + acc[r].y * a2.y + acc[r].z * a2.z + acc[r].w * a2.w;
        #pragma unroll
        for (int off = 16; off; off >>= 1) {
            p1 += __shfl_xor(p1, off);
            p2 += __shfl_xor(p2, off);
        }
        int gr = row0 + rg + r;
        if ((tid & 31) == 0 && gr < NNODES) { s1[gr] = p1; s2[gr] = p2; }
    }
}

// ---------------------------------------------------------------------------
// K2: per-edge e = leaky_relu(s1[row]+s2[col]); rowsum += e; count[row]++
// ---------------------------------------------------------------------------
__global__ void edge_phase1(const int* __restrict__ ei,
                            const float* __restrict__ s1,
                            const float* __restrict__ s2,
                            float* __restrict__ e,
                            float* __restrict__ rowsum,
                            int* __restrict__ count) {
    int i = blockIdx.x * blockDim.x + threadIdx.x;
    if (i >= NEDGES) return;
    int r = ei[i];
    int c = ei[NEDGES + i];
    float s = s1[r] + s2[c];
    float ev = (s >= 0.f) ? s : ALPHA * s;
    e[i] = ev;
    atomicAdd(&rowsum[r], ev);
    atomicAdd(&count[r], 1);
}

// ---------------------------------------------------------------------------
// K3a: per-chunk sums (196 blocks x 256 rows)
// ---------------------------------------------------------------------------
__global__ __launch_bounds__(256) void chunk_sums(const int* __restrict__ count,
                                                  int* __restrict__ chunkSum) {
    __shared__ int red[256];
    int t = threadIdx.x;
    int idx = blockIdx.x * 256 + t;
    red[t] = (idx < NNODES) ? count[idx] : 0;
    __syncthreads();
    #pragma unroll
    for (int off = 128; off; off >>= 1) {
        if (t < off) red[t] += red[t + off];
        __syncthreads();
    }
    if (t == 0) chunkSum[blockIdx.x] = red[0];
}

// ---------------------------------------------------------------------------
// K3b: scan 196 chunk sums (single 256-thread block, LDS Hillis-Steele)
// ---------------------------------------------------------------------------
__global__ __launch_bounds__(256) void scan_chunks(const int* __restrict__ chunkSum,
                                                   int* __restrict__ chunkBase,
                                                   int* __restrict__ rowstart) {
    __shared__ int s[256];
    int t = threadIdx.x;
    int v = (t < NBLK) ? chunkSum[t] : 0;
    s[t] = v;
    __syncthreads();
    #pragma unroll
    for (int off = 1; off < 256; off <<= 1) {
        int x = (t >= off) ? s[t - off] : 0;
        __syncthreads();
        s[t] += x;
        __syncthreads();
    }
    if (t < NBLK) chunkBase[t] = s[t] - v;     // exclusive prefix
    if (t == 255) rowstart[NNODES] = s[255];   // total edge count
}

// ---------------------------------------------------------------------------
// K3c: local 256-element scan + chunk base -> rowstart, cursor
// ---------------------------------------------------------------------------
__global__ __launch_bounds__(256) void write_rowstart(const int* __restrict__ count,
                                                      const int* __restrict__ chunkBase,
                                                      int* __restrict__ rowstart,
                                                      int* __restrict__ cursor) {
    __shared__ int s[256];
    int t = threadIdx.x;
    int idx = blockIdx.x * 256 + t;
    int v = (idx < NNODES) ? count[idx] : 0;
    s[t] = v;
    __syncthreads();
    #pragma unroll
    for (int off = 1; off < 256; off <<= 1) {
        int x = (t >= off) ? s[t - off] : 0;
        __syncthreads();
        s[t] += x;
        __syncthreads();
    }
    int ex = chunkBase[blockIdx.x] + s[t] - v;
    if (idx < NNODES) { rowstart[idx] = ex; cursor[idx] = ex; }
}

// ---------------------------------------------------------------------------
// K4: scatter edges into CSR order; store e_exp = exp(e - rowsum[row]) and col
// ---------------------------------------------------------------------------
__global__ void scatter_kernel(const int* __restrict__ ei,
                               const float* __restrict__ e,
                               const float* __restrict__ rowsum,
                               int* __restrict__ cursor,
                               float* __restrict__ sEexp,
                               int* __restrict__ sCol) {
    int i = blockIdx.x * blockDim.x + threadIdx.x;
    if (i >= NEDGES) return;
    int r = ei[i];
    int c = ei[NEDGES + i];
    int pos = atomicAdd(&cursor[r], 1);
    sEexp[pos] = expf(e[i] - rowsum[r]);
    sCol[pos] = c;
}

// ---------------------------------------------------------------------------
// K5: per-row aggregation. One wave per row:
//   denom = sum(e_exp) + EPS;  out[row] = sum (e_exp/denom) * Wh[col]
// ---------------------------------------------------------------------------
__global__ __launch_bounds__(256) void aggregate(const int* __restrict__ rowstart,
                                                 const float* __restrict__ sEexp,
                                                 const int* __restrict__ sCol,
                                                 const float* __restrict__ Wh,
                                                 float* __restrict__ out) {
    const int wid = threadIdx.x >> 6;
    const int lane = threadIdx.x & 63;
    const int row = blockIdx.x * 4 + wid;
    if (row >= NNODES) return;
    const int start = rowstart[row];
    const int end = rowstart[row + 1];

    float ssum = 0.f;
    for (int j = start + lane; j < end; j += 64) ssum += sEexp[j];
    #pragma unroll
    for (int off = 32; off; off >>= 1) ssum += __shfl_xor(ssum, off);
    const float invd = 1.0f / (ssum + EPS);

    float acc0 = 0.f, acc1 = 0.f;
    for (int j = start; j < end; ++j) {
        float w = sEexp[j] * invd;
        int c = sCol[j];
        const float* wh = Wh + (long)c * NF;
        acc0 += w * wh[lane];
        acc1 += w * wh[64 + lane];
    }
    out[row * NF + lane] = acc0;
    out[row * NF + 64 + lane] = acc1;
}

// ---------------------------------------------------------------------------
extern "C" void kernel_launch(void* const* d_in, const int* in_sizes, int n_in,
                              void* d_out, int out_size, void* d_ws, size_t ws_size,
                              hipStream_t stream) {
    const float* h  = (const float*)d_in[0];
    const int*   ei = (const int*)d_in[1];
    const float* W  = (const float*)d_in[2];
    const float* a  = (const float*)d_in[3];
    float* out = (float*)d_out;

    char* ws = (char*)d_ws;
    size_t off = 0;
    auto alloc = [&](size_t bytes) -> void* {
        void* p = ws + off;
        off += (bytes + 255) & ~(size_t)255;
        return p;
    };

    float* Wh      = (float*)alloc((size_t)NNODES * NF * 4);
    float* rowsum  = (float*)alloc((size_t)NNODES * 4);
    int*   count   = (int*)alloc((size_t)NNODES * 4);
    float* s1      = (float*)alloc((size_t)NNODES * 4);
    float* s2      = (float*)alloc((size_t)NNODES * 4);
    int*   rowstart= (int*)alloc((size_t)(NNODES + 1) * 4);
    int*   cursor  = (int*)alloc((size_t)NNODES * 4);
    float* e       = (float*)alloc((size_t)NEDGES * 4);
    float* sEexp   = (float*)alloc((size_t)NEDGES * 4);
    int*   sCol    = (int*)alloc((size_t)NEDGES * 4);
    int*   chunkSum= (int*)alloc((size_t)NBLK * 4);
    int*   chunkBase=(int*)alloc((size_t)NBLK * 4);

    hipMemsetAsync(rowsum, 0, (size_t)NNODES * 4, stream);
    hipMemsetAsync(count, 0, (size_t)NNODES * 4, stream);

    // K1: GEMM + fused s1/s2
    gemm_wh<<<(NNODES + 63) / 64, 256, 0, stream>>>(h, W, a, Wh, s1, s2);
    // K2: per-edge scores + histogram + rowsum
    edge_phase1<<<(NEDGES + 255) / 256, 256, 0, stream>>>(ei, s1, s2, e, rowsum, count);
    // K3: hierarchical scan (3 fast kernels)
    chunk_sums<<<NBLK, 256, 0, stream>>>(count, chunkSum);
    scan_chunks<<<1, 256, 0, stream>>>(chunkSum, chunkBase, rowstart);
    write_rowstart<<<NBLK, 256, 0, stream>>>(count, chunkBase, rowstart, cursor);
    // K4: scatter into CSR order with e_exp
    scatter_kernel<<<(NEDGES + 255) / 256, 256, 0, stream>>>(ei, e, rowsum, cursor, sEexp, sCol);
    // K5: aggregate
    aggregate<<<(NNODES + 3) / 4, 256, 0, stream>>>(rowstart, sEexp, sCol, Wh, out);
}

// Round 3
// 239.528 us; speedup vs baseline: 1.6463x; 1.1868x over previous
//
#include <hip/hip_runtime.h>
#include <hip/hip_bf16.h>
#include <math.h>

#define NNODES 50000
#define NF 128
#define NEDGES 800000
#define ALPHA 0.2f
#define EPS 1e-16f
#define NBLK 196            // ceil(50000/256) chunks for the hierarchical scan

// ---------------------------------------------------------------------------
// K1: Wh = h @ W  (50000x128 @ 128x128, f32)  + fused s1/s2 epilogue
// ---------------------------------------------------------------------------
__global__ __launch_bounds__(256) void gemm_wh(const float* __restrict__ h,
                                               const float* __restrict__ W,
                                               const float* __restrict__ a,
                                               float* __restrict__ Wh,
                                               float* __restrict__ s1,
                                               float* __restrict__ s2) {
    __shared__ float hs[64][128];
    const int tid = threadIdx.x;
    const int row0 = blockIdx.x * 64;

    #pragma unroll
    for (int i = 0; i < 32; ++i) {
        int idx = tid + i * 256;
        int r = idx >> 7, c = idx & 127;
        int gr = row0 + r;
        hs[r][c] = (gr < NNODES) ? h[gr * NF + c] : 0.f;
    }
    __syncthreads();

    const int c4 = (tid & 31) * 4;      // output columns c4..c4+3
    const int rg = (tid >> 5) * 8;      // first of 8 rows

    float4 acc[8];
    #pragma unroll
    for (int r = 0; r < 8; ++r) acc[r] = make_float4(0.f, 0.f, 0.f, 0.f);

    for (int k = 0; k < 128; k += 4) {
        float4 w0 = *(const float4*)&W[(k + 0) * NF + c4];
        float4 w1 = *(const float4*)&W[(k + 1) * NF + c4];
        float4 w2 = *(const float4*)&W[(k + 2) * NF + c4];
        float4 w3 = *(const float4*)&W[(k + 3) * NF + c4];
        #pragma unroll
        for (int r = 0; r < 8; ++r) {
            float4 hv = *(const float4*)&hs[rg + r][k];
            acc[r].x += hv.x * w0.x + hv.y * w1.x + hv.z * w2.x + hv.w * w3.x;
            acc[r].y += hv.x * w0.y + hv.y * w1.y + hv.z * w2.y + hv.w * w3.y;
            acc[r].z += hv.x * w0.z + hv.y * w1.z + hv.z * w2.z + hv.w * w3.z;
            acc[r].w += hv.x * w0.w + hv.y * w1.w + hv.z * w2.w + hv.w * w3.w;
        }
    }

    #pragma unroll
    for (int r = 0; r < 8; ++r) {
        int gr = row0 + rg + r;
        if (gr < NNODES) *(float4*)&Wh[gr * NF + c4] = acc[r];
    }

    // fused s1/s2
    float4 a1 = *(const float4*)&a[c4];
    float4 a2 = *(const float4*)&a[128 + c4];
    #pragma unroll
    for (int r = 0; r < 8; ++r) {
        float p1 = acc[r].x * a1.x + acc[r].y * a1.y + acc[r].z * a1.z + acc[r].w * a1.w;
        float p2 = acc[r].x * a2.x + acc[r].y * a2.y + acc[r].z * a2.z + acc[r].w * a2.w;
        #pragma unroll
        for (int off = 16; off; off >>= 1) {
            p1 += __shfl_xor(p1, off);
            p2 += __shfl_xor(p2, off);
        }
        int gr = row0 + rg + r;
        if ((tid & 31) == 0 && gr < NNODES) { s1[gr] = p1; s2[gr] = p2; }
    }
}

// ---------------------------------------------------------------------------
// K2: per-edge degree histogram (count only)
// ---------------------------------------------------------------------------
__global__ void count_kernel(const int* __restrict__ ei,
                             int* __restrict__ count) {
    int i = blockIdx.x * blockDim.x + threadIdx.x;
    if (i >= NEDGES) return;
    atomicAdd(&count[ei[i]], 1);
}

// ---------------------------------------------------------------------------
// K3a: per-chunk sums
// ---------------------------------------------------------------------------
__global__ __launch_bounds__(256) void chunk_sums(const int* __restrict__ count,
                                                  int* __restrict__ chunkSum) {
    __shared__ int red[256];
    int t = threadIdx.x;
    int idx = blockIdx.x * 256 + t;
    red[t] = (idx < NNODES) ? count[idx] : 0;
    __syncthreads();
    #pragma unroll
    for (int off = 128; off; off >>= 1) {
        if (t < off) red[t] += red[t + off];
        __syncthreads();
    }
    if (t == 0) chunkSum[blockIdx.x] = red[0];
}

// ---------------------------------------------------------------------------
// K3b: scan chunk sums (single 256-thread block)
// ---------------------------------------------------------------------------
__global__ __launch_bounds__(256) void scan_chunks(const int* __restrict__ chunkSum,
                                                   int* __restrict__ chunkBase,
                                                   int* __restrict__ rowstart) {
    __shared__ int s[256];
    int t = threadIdx.x;
    int v = (t < NBLK) ? chunkSum[t] : 0;
    s[t] = v;
    __syncthreads();
    #pragma unroll
    for (int off = 1; off < 256; off <<= 1) {
        int x = (t >= off) ? s[t - off] : 0;
        __syncthreads();
        s[t] += x;
        __syncthreads();
    }
    if (t < NBLK) chunkBase[t] = s[t] - v;
    if (t == 255) rowstart[NNODES] = s[255];
}

// ---------------------------------------------------------------------------
// K3c: local scan + chunk base -> rowstart, cursor
// ---------------------------------------------------------------------------
__global__ __launch_bounds__(256) void write_rowstart(const int* __restrict__ count,
                                                      const int* __restrict__ chunkBase,
                                                      int* __restrict__ rowstart,
                                                      int* __restrict__ cursor) {
    __shared__ int s[256];
    int t = threadIdx.x;
    int idx = blockIdx.x * 256 + t;
    int v = (idx < NNODES) ? count[idx] : 0;
    s[t] = v;
    __syncthreads();
    #pragma unroll
    for (int off = 1; off < 256; off <<= 1) {
        int x = (t >= off) ? s[t - off] : 0;
        __syncthreads();
        s[t] += x;
        __syncthreads();
    }
    int ex = chunkBase[blockIdx.x] + s[t] - v;
    if (idx < NNODES) { rowstart[idx] = ex; cursor[idx] = ex; }
}

// ---------------------------------------------------------------------------
// K4: single edge pass: score, rowsum atomic, scatter (e, col) pair into CSR
// ---------------------------------------------------------------------------
__global__ void edge_kernel(const int* __restrict__ ei,
                            const float* __restrict__ s1,
                            const float* __restrict__ s2,
                            float* __restrict__ rowsum,
                            int* __restrict__ cursor,
                            float2* __restrict__ pair) {
    int i = blockIdx.x * blockDim.x + threadIdx.x;
    if (i >= NEDGES) return;
    int r = ei[i];
    int c = ei[NEDGES + i];
    float s = s1[r] + s2[c];
    float ev = (s >= 0.f) ? s : ALPHA * s;
    atomicAdd(&rowsum[r], ev);
    int pos = atomicAdd(&cursor[r], 1);
    pair[pos] = make_float2(ev, __int_as_float(c));
}

// ---------------------------------------------------------------------------
// K5: per-row aggregation, one wave per row.
//   pass A: denom = sum exp(e - rs)   (lane-parallel)
//   pass B: acc += (exp(e - rs)/denom) * Wh[col]  (x4 unroll, float2 gathers)
// ---------------------------------------------------------------------------
__global__ __launch_bounds__(256) void aggregate(const int* __restrict__ rowstart,
                                                 const float* __restrict__ rowsum,
                                                 const float2* __restrict__ pair,
                                                 const float* __restrict__ Wh,
                                                 float* __restrict__ out) {
    const int wid = threadIdx.x >> 6;
    const int lane = threadIdx.x & 63;
    const int row = blockIdx.x * 4 + wid;
    if (row >= NNODES) return;
    const int start = rowstart[row];
    const int end = rowstart[row + 1];
    const float rs = rowsum[row];

    // pass A: denominator
    float ssum = 0.f;
    for (int j = start + lane; j < end; j += 64) {
        float2 p = pair[j];
        ssum += expf(p.x - rs);
    }
    #pragma unroll
    for (int off = 32; off; off >>= 1) ssum += __shfl_xor(ssum, off);
    const float invd = 1.0f / (ssum + EPS);

    // pass B: weighted gather-accumulate, 4 gathers in flight
    float accx = 0.f, accy = 0.f;
    int j = start;
    for (; j + 4 <= end; j += 4) {
        float2 p0 = pair[j + 0];
        float2 p1 = pair[j + 1];
        float2 p2 = pair[j + 2];
        float2 p3 = pair[j + 3];
        const float2* w0 = (const float2*)(Wh + (long)__float_as_int(p0.y) * NF);
        const float2* w1 = (const float2*)(Wh + (long)__float_as_int(p1.y) * NF);
        const float2* w2 = (const float2*)(Wh + (long)__float_as_int(p2.y) * NF);
        const float2* w3 = (const float2*)(Wh + (long)__float_as_int(p3.y) * NF);
        float2 v0 = w0[lane];
        float2 v1 = w1[lane];
        float2 v2 = w2[lane];
        float2 v3 = w3[lane];
        float a0 = expf(p0.x - rs) * invd;
        float a1 = expf(p1.x - rs) * invd;
        float a2 = expf(p2.x - rs) * invd;
        float a3 = expf(p3.x - rs) * invd;
        accx += a0 * v0.x + a1 * v1.x + a2 * v2.x + a3 * v3.x;
        accy += a0 * v0.y + a1 * v1.y + a2 * v2.y + a3 * v3.y;
    }
    for (; j < end; ++j) {
        float2 p = pair[j];
        const float2* w = (const float2*)(Wh + (long)__float_as_int(p.y) * NF);
        float2 v = w[lane];
        float aw = expf(p.x - rs) * invd;
        accx += aw * v.x;
        accy += aw * v.y;
    }
    ((float2*)&out[row * NF])[lane] = make_float2(accx, accy);
}

// ---------------------------------------------------------------------------
extern "C" void kernel_launch(void* const* d_in, const int* in_sizes, int n_in,
                              void* d_out, int out_size, void* d_ws, size_t ws_size,
                              hipStream_t stream) {
    const float* h  = (const float*)d_in[0];
    const int*   ei = (const int*)d_in[1];
    const float* W  = (const float*)d_in[2];
    const float* a  = (const float*)d_in[3];
    float* out = (float*)d_out;

    char* ws = (char*)d_ws;
    size_t off = 0;
    auto alloc = [&](size_t bytes) -> void* {
        void* p = ws + off;
        off += (bytes + 255) & ~(size_t)255;
        return p;
    };

    float*  Wh       = (float*)alloc((size_t)NNODES * NF * 4);
    float*  rowsum   = (float*)alloc((size_t)NNODES * 4);
    int*    count    = (int*)alloc((size_t)NNODES * 4);
    float*  s1       = (float*)alloc((size_t)NNODES * 4);
    float*  s2       = (float*)alloc((size_t)NNODES * 4);
    int*    rowstart = (int*)alloc((size_t)(NNODES + 1) * 4);
    int*    cursor   = (int*)alloc((size_t)NNODES * 4);
    float2* pair     = (float2*)alloc((size_t)NEDGES * 8);
    int*    chunkSum = (int*)alloc((size_t)NBLK * 4);
    int*    chunkBase= (int*)alloc((size_t)NBLK * 4);

    hipMemsetAsync(rowsum, 0, (size_t)NNODES * 4, stream);
    hipMemsetAsync(count, 0, (size_t)NNODES * 4, stream);

    // K1: GEMM + fused s1/s2
    gemm_wh<<<(NNODES + 63) / 64, 256, 0, stream>>>(h, W, a, Wh, s1, s2);
    // K2: degree histogram
    count_kernel<<<(NEDGES + 255) / 256, 256, 0, stream>>>(ei, count);
    // K3: hierarchical scan
    chunk_sums<<<NBLK, 256, 0, stream>>>(count, chunkSum);
    scan_chunks<<<1, 256, 0, stream>>>(chunkSum, chunkBase, rowstart);
    write_rowstart<<<NBLK, 256, 0, stream>>>(count, chunkBase, rowstart, cursor);
    // K4: single edge pass (score + rowsum + CSR scatter)
    edge_kernel<<<(NEDGES + 255) / 256, 256, 0, stream>>>(ei, s1, s2, rowsum, cursor, pair);
    // K5: aggregate (exp computed inline)
    aggregate<<<(NNODES + 3) / 4, 256, 0, stream>>>(rowstart, rowsum, pair, Wh, out);
}

// Round 4
// 177.543 us; speedup vs baseline: 2.2211x; 1.3491x over previous
//
#include <hip/hip_runtime.h>
#include <hip/hip_bf16.h>
#include <math.h>

#define NNODES 50000
#define NF 128
#define NEDGES 800000
#define ALPHA 0.2f
#define EPS 1e-16f
#define NBLK 196            // ceil(50000/256) chunks for the hierarchical scan
#define EPT 4               // edges per thread in edge passes

// ---------------------------------------------------------------------------
// K1: Wh = h @ W  (50000x128 @ 128x128, f32)  + fused s1/s2 epilogue
// ---------------------------------------------------------------------------
__global__ __launch_bounds__(256) void gemm_wh(const float* __restrict__ h,
                                               const float* __restrict__ W,
                                               const float* __restrict__ a,
                                               float* __restrict__ Wh,
                                               float* __restrict__ s1,
                                               float* __restrict__ s2) {
    __shared__ float hs[64][128];
    const int tid = threadIdx.x;
    const int row0 = blockIdx.x * 64;

    #pragma unroll
    for (int i = 0; i < 32; ++i) {
        int idx = tid + i * 256;
        int r = idx >> 7, c = idx & 127;
        int gr = row0 + r;
        hs[r][c] = (gr < NNODES) ? h[gr * NF + c] : 0.f;
    }
    __syncthreads();

    const int c4 = (tid & 31) * 4;      // output columns c4..c4+3
    const int rg = (tid >> 5) * 8;      // first of 8 rows

    float4 acc[8];
    #pragma unroll
    for (int r = 0; r < 8; ++r) acc[r] = make_float4(0.f, 0.f, 0.f, 0.f);

    for (int k = 0; k < 128; k += 4) {
        float4 w0 = *(const float4*)&W[(k + 0) * NF + c4];
        float4 w1 = *(const float4*)&W[(k + 1) * NF + c4];
        float4 w2 = *(const float4*)&W[(k + 2) * NF + c4];
        float4 w3 = *(const float4*)&W[(k + 3) * NF + c4];
        #pragma unroll
        for (int r = 0; r < 8; ++r) {
            float4 hv = *(const float4*)&hs[rg + r][k];
            acc[r].x += hv.x * w0.x + hv.y * w1.x + hv.z * w2.x + hv.w * w3.x;
            acc[r].y += hv.x * w0.y + hv.y * w1.y + hv.z * w2.y + hv.w * w3.y;
            acc[r].z += hv.x * w0.z + hv.y * w1.z + hv.z * w2.z + hv.w * w3.z;
            acc[r].w += hv.x * w0.w + hv.y * w1.w + hv.z * w2.w + hv.w * w3.w;
        }
    }

    #pragma unroll
    for (int r = 0; r < 8; ++r) {
        int gr = row0 + rg + r;
        if (gr < NNODES) *(float4*)&Wh[gr * NF + c4] = acc[r];
    }

    // fused s1/s2
    float4 a1 = *(const float4*)&a[c4];
    float4 a2 = *(const float4*)&a[128 + c4];
    #pragma unroll
    for (int r = 0; r < 8; ++r) {
        float p1 = acc[r].x * a1.x + acc[r].y * a1.y + acc[r].z * a1.z + acc[r].w * a1.w;
        float p2 = acc[r].x * a2.x + acc[r].y * a2.y + acc[r].z * a2.z + acc[r].w * a2.w;
        #pragma unroll
        for (int off = 16; off; off >>= 1) {
            p1 += __shfl_xor(p1, off);
            p2 += __shfl_xor(p2, off);
        }
        int gr = row0 + rg + r;
        if ((tid & 31) == 0 && gr < NNODES) { s1[gr] = p1; s2[gr] = p2; }
    }
}

// ---------------------------------------------------------------------------
// K2: degree histogram + per-edge rank (4 independent atomic chains/thread)
// ---------------------------------------------------------------------------
__global__ __launch_bounds__(256) void count_rank(const int* __restrict__ ei,
                                                  int* __restrict__ count,
                                                  int* __restrict__ rank) {
    const int base = blockIdx.x * blockDim.x + threadIdx.x;
    const int stride = gridDim.x * blockDim.x;
    int idx[EPT], r[EPT];
    #pragma unroll
    for (int k = 0; k < EPT; ++k) {
        idx[k] = base + k * stride;
        r[k] = (idx[k] < NEDGES) ? ei[idx[k]] : -1;
    }
    int rk[EPT];
    #pragma unroll
    for (int k = 0; k < EPT; ++k)
        if (r[k] >= 0) rk[k] = atomicAdd(&count[r[k]], 1);
    #pragma unroll
    for (int k = 0; k < EPT; ++k)
        if (r[k] >= 0) rank[idx[k]] = rk[k];
}

// ---------------------------------------------------------------------------
// K3a: per-chunk sums
// ---------------------------------------------------------------------------
__global__ __launch_bounds__(256) void chunk_sums(const int* __restrict__ count,
                                                  int* __restrict__ chunkSum) {
    __shared__ int red[256];
    int t = threadIdx.x;
    int idx = blockIdx.x * 256 + t;
    red[t] = (idx < NNODES) ? count[idx] : 0;
    __syncthreads();
    #pragma unroll
    for (int off = 128; off; off >>= 1) {
        if (t < off) red[t] += red[t + off];
        __syncthreads();
    }
    if (t == 0) chunkSum[blockIdx.x] = red[0];
}

// ---------------------------------------------------------------------------
// K3b: scan chunk sums (single 256-thread block)
// ---------------------------------------------------------------------------
__global__ __launch_bounds__(256) void scan_chunks(const int* __restrict__ chunkSum,
                                                   int* __restrict__ chunkBase,
                                                   int* __restrict__ rowstart) {
    __shared__ int s[256];
    int t = threadIdx.x;
    int v = (t < NBLK) ? chunkSum[t] : 0;
    s[t] = v;
    __syncthreads();
    #pragma unroll
    for (int off = 1; off < 256; off <<= 1) {
        int x = (t >= off) ? s[t - off] : 0;
        __syncthreads();
        s[t] += x;
        __syncthreads();
    }
    if (t < NBLK) chunkBase[t] = s[t] - v;
    if (t == 255) rowstart[NNODES] = s[255];
}

// ---------------------------------------------------------------------------
// K3c: local scan + chunk base -> rowstart
// ---------------------------------------------------------------------------
__global__ __launch_bounds__(256) void write_rowstart(const int* __restrict__ count,
                                                      const int* __restrict__ chunkBase,
                                                      int* __restrict__ rowstart) {
    __shared__ int s[256];
    int t = threadIdx.x;
    int idx = blockIdx.x * 256 + t;
    int v = (idx < NNODES) ? count[idx] : 0;
    s[t] = v;
    __syncthreads();
    #pragma unroll
    for (int off = 1; off < 256; off <<= 1) {
        int x = (t >= off) ? s[t - off] : 0;
        __syncthreads();
        s[t] += x;
        __syncthreads();
    }
    if (idx < NNODES) rowstart[idx] = chunkBase[blockIdx.x] + s[t] - v;
}

// ---------------------------------------------------------------------------
// K4: scatter pass — NO atomics: pos = rowstart[r] + rank[i]
//     e = leaky_relu(s1[r] + s2[c]); pair[pos] = (e, col)
// ---------------------------------------------------------------------------
__global__ __launch_bounds__(256) void scatter_edges(const int* __restrict__ ei,
                                                     const int* __restrict__ rank,
                                                     const int* __restrict__ rowstart,
                                                     const float* __restrict__ s1,
                                                     const float* __restrict__ s2,
                                                     float2* __restrict__ pair) {
    const int base = blockIdx.x * blockDim.x + threadIdx.x;
    const int stride = gridDim.x * blockDim.x;
    int idx[EPT], r[EPT], c[EPT], rk[EPT];
    #pragma unroll
    for (int k = 0; k < EPT; ++k) {
        idx[k] = base + k * stride;
        if (idx[k] < NEDGES) {
            r[k] = ei[idx[k]];
            c[k] = ei[NEDGES + idx[k]];
            rk[k] = rank[idx[k]];
        } else r[k] = -1;
    }
    float sv1[EPT], sv2[EPT];
    int rs[EPT];
    #pragma unroll
    for (int k = 0; k < EPT; ++k)
        if (r[k] >= 0) { sv1[k] = s1[r[k]]; sv2[k] = s2[c[k]]; rs[k] = rowstart[r[k]]; }
    #pragma unroll
    for (int k = 0; k < EPT; ++k)
        if (r[k] >= 0) {
            float s = sv1[k] + sv2[k];
            float ev = (s >= 0.f) ? s : ALPHA * s;
            pair[rs[k] + rk[k]] = make_float2(ev, __int_as_float(c[k]));
        }
}

// ---------------------------------------------------------------------------
// K5: per-row aggregation, one wave per row.
//   pass A1: rs = sum(e)            (replicates reference's rowsum shift)
//   pass A2: denom = sum exp(e-rs)
//   pass B : acc += (exp(e-rs)/denom) * Wh[col]  (x4 unroll, float2 gathers)
// ---------------------------------------------------------------------------
__global__ __launch_bounds__(256) void aggregate(const int* __restrict__ rowstart,
                                                 const float2* __restrict__ pair,
                                                 const float* __restrict__ Wh,
                                                 float* __restrict__ out) {
    const int wid = threadIdx.x >> 6;
    const int lane = threadIdx.x & 63;
    const int row = blockIdx.x * 4 + wid;
    if (row >= NNODES) return;
    const int start = rowstart[row];
    const int end = rowstart[row + 1];

    // pass A1: row-sum of e
    float esum = 0.f;
    for (int j = start + lane; j < end; j += 64) esum += pair[j].x;
    #pragma unroll
    for (int off = 32; off; off >>= 1) esum += __shfl_xor(esum, off);
    const float rs = esum;

    // pass A2: denominator
    float dsum = 0.f;
    for (int j = start + lane; j < end; j += 64) dsum += expf(pair[j].x - rs);
    #pragma unroll
    for (int off = 32; off; off >>= 1) dsum += __shfl_xor(dsum, off);
    const float invd = 1.0f / (dsum + EPS);

    // pass B: weighted gather-accumulate, 4 gathers in flight
    float accx = 0.f, accy = 0.f;
    int j = start;
    for (; j + 4 <= end; j += 4) {
        float2 p0 = pair[j + 0];
        float2 p1 = pair[j + 1];
        float2 p2 = pair[j + 2];
        float2 p3 = pair[j + 3];
        const float2* w0 = (const float2*)(Wh + (long)__float_as_int(p0.y) * NF);
        const float2* w1 = (const float2*)(Wh + (long)__float_as_int(p1.y) * NF);
        const float2* w2 = (const float2*)(Wh + (long)__float_as_int(p2.y) * NF);
        const float2* w3 = (const float2*)(Wh + (long)__float_as_int(p3.y) * NF);
        float2 v0 = w0[lane];
        float2 v1 = w1[lane];
        float2 v2 = w2[lane];
        float2 v3 = w3[lane];
        float a0 = expf(p0.x - rs) * invd;
        float a1 = expf(p1.x - rs) * invd;
        float a2 = expf(p2.x - rs) * invd;
        float a3 = expf(p3.x - rs) * invd;
        accx += a0 * v0.x + a1 * v1.x + a2 * v2.x + a3 * v3.x;
        accy += a0 * v0.y + a1 * v1.y + a2 * v2.y + a3 * v3.y;
    }
    for (; j < end; ++j) {
        float2 p = pair[j];
        const float2* w = (const float2*)(Wh + (long)__float_as_int(p.y) * NF);
        float2 v = w[lane];
        float aw = expf(p.x - rs) * invd;
        accx += aw * v.x;
        accy += aw * v.y;
    }
    ((float2*)&out[row * NF])[lane] = make_float2(accx, accy);
}

// ---------------------------------------------------------------------------
extern "C" void kernel_launch(void* const* d_in, const int* in_sizes, int n_in,
                              void* d_out, int out_size, void* d_ws, size_t ws_size,
                              hipStream_t stream) {
    const float* h  = (const float*)d_in[0];
    const int*   ei = (const int*)d_in[1];
    const float* W  = (const float*)d_in[2];
    const float* a  = (const float*)d_in[3];
    float* out = (float*)d_out;

    char* ws = (char*)d_ws;
    size_t off = 0;
    auto alloc = [&](size_t bytes) -> void* {
        void* p = ws + off;
        off += (bytes + 255) & ~(size_t)255;
        return p;
    };

    float*  Wh       = (float*)alloc((size_t)NNODES * NF * 4);
    int*    count    = (int*)alloc((size_t)NNODES * 4);
    float*  s1       = (float*)alloc((size_t)NNODES * 4);
    float*  s2       = (float*)alloc((size_t)NNODES * 4);
    int*    rowstart = (int*)alloc((size_t)(NNODES + 1) * 4);
    int*    rank     = (int*)alloc((size_t)NEDGES * 4);
    float2* pair     = (float2*)alloc((size_t)NEDGES * 8);
    int*    chunkSum = (int*)alloc((size_t)NBLK * 4);
    int*    chunkBase= (int*)alloc((size_t)NBLK * 4);

    hipMemsetAsync(count, 0, (size_t)NNODES * 4, stream);

    const int edgeThreads = NEDGES / EPT;                 // 200000
    const int edgeBlocks = (edgeThreads + 255) / 256;     // 782

    // K1: GEMM + fused s1/s2
    gemm_wh<<<(NNODES + 63) / 64, 256, 0, stream>>>(h, W, a, Wh, s1, s2);
    // K2: histogram + rank
    count_rank<<<edgeBlocks, 256, 0, stream>>>(ei, count, rank);
    // K3: hierarchical scan
    chunk_sums<<<NBLK, 256, 0, stream>>>(count, chunkSum);
    scan_chunks<<<1, 256, 0, stream>>>(chunkSum, chunkBase, rowstart);
    write_rowstart<<<NBLK, 256, 0, stream>>>(count, chunkBase, rowstart);
    // K4: atomic-free scatter
    scatter_edges<<<edgeBlocks, 256, 0, stream>>>(ei, rank, rowstart, s1, s2, pair);
    // K5: aggregate (rowsum + exp computed inline)
    aggregate<<<(NNODES + 3) / 4, 256, 0, stream>>>(rowstart, pair, Wh, out);
}

// Round 6
// 145.823 us; speedup vs baseline: 2.7042x; 1.2175x over previous
//
#include <hip/hip_runtime.h>
#include <hip/hip_bf16.h>
#include <math.h>

#define NNODES 50000
#define NF 128
#define NEDGES 800000
#define ALPHA 0.2f
#define EPS 1e-16f
#define NBLK 196            // ceil(50000/256) chunks for the hierarchical scan
#define EPT 8               // edges per thread in edge passes
#define GEMM_BLOCKS 782     // ceil(50000/64)
#define CNT_BLOCKS 391      // ceil(800000/(8*256))
#define MAXDEG 128          // LDS weight-cache fast path limit (expected max deg ~35)

// bf16 RNE pack helpers
__device__ inline unsigned bf16rne(float x) {
    unsigned u = __float_as_uint(x);
    return (u + 0x7FFFu + ((u >> 16) & 1u)) >> 16;
}
__device__ inline unsigned pack2bf(float lo, float hi) {
    return bf16rne(lo) | (bf16rne(hi) << 16);
}

// ---------------------------------------------------------------------------
// K1 (fat): blocks [0, GEMM_BLOCKS): Wh_bf16 = bf16(h @ W) + fused s1/s2.
//           blocks [GEMM_BLOCKS, +CNT_BLOCKS): degree histogram + edge rank.
// GEMM part is VALU/LDS-bound; count part is atomic-latency-bound — co-residency
// (5 blocks/CU by 32KB LDS) overlaps them.
// ---------------------------------------------------------------------------
__global__ __launch_bounds__(256) void gemm_count(const float* __restrict__ h,
                                                  const float* __restrict__ W,
                                                  const float* __restrict__ a,
                                                  const int* __restrict__ ei,
                                                  unsigned* __restrict__ WhB,
                                                  float* __restrict__ s1,
                                                  float* __restrict__ s2,
                                                  int* __restrict__ count,
                                                  int* __restrict__ rank) {
    __shared__ float hs[64][128];
    const int tid = threadIdx.x;

    if (blockIdx.x >= GEMM_BLOCKS) {
        // ---- histogram + rank part ----
        const int base = (blockIdx.x - GEMM_BLOCKS) * 256 + tid;
        const int stride = CNT_BLOCKS * 256;
        int idx[EPT], r[EPT];
        #pragma unroll
        for (int k = 0; k < EPT; ++k) {
            idx[k] = base + k * stride;
            r[k] = (idx[k] < NEDGES) ? ei[idx[k]] : -1;
        }
        int rk[EPT];
        #pragma unroll
        for (int k = 0; k < EPT; ++k)
            if (r[k] >= 0) rk[k] = atomicAdd(&count[r[k]], 1);
        #pragma unroll
        for (int k = 0; k < EPT; ++k)
            if (r[k] >= 0) rank[idx[k]] = rk[k];
        return;
    }

    // ---- GEMM part ----
    const int row0 = blockIdx.x * 64;

    #pragma unroll
    for (int i = 0; i < 32; ++i) {
        int idx = tid + i * 256;
        int r = idx >> 7, c = idx & 127;
        int gr = row0 + r;
        hs[r][c] = (gr < NNODES) ? h[gr * NF + c] : 0.f;
    }
    __syncthreads();

    const int c4 = (tid & 31) * 4;      // output columns c4..c4+3
    const int rg = (tid >> 5) * 8;      // first of 8 rows

    float4 acc[8];
    #pragma unroll
    for (int r = 0; r < 8; ++r) acc[r] = make_float4(0.f, 0.f, 0.f, 0.f);

    for (int k = 0; k < 128; k += 4) {
        float4 w0 = *(const float4*)&W[(k + 0) * NF + c4];
        float4 w1 = *(const float4*)&W[(k + 1) * NF + c4];
        float4 w2 = *(const float4*)&W[(k + 2) * NF + c4];
        float4 w3 = *(const float4*)&W[(k + 3) * NF + c4];
        #pragma unroll
        for (int r = 0; r < 8; ++r) {
            float4 hv = *(const float4*)&hs[rg + r][k];
            acc[r].x += hv.x * w0.x + hv.y * w1.x + hv.z * w2.x + hv.w * w3.x;
            acc[r].y += hv.x * w0.y + hv.y * w1.y + hv.z * w2.y + hv.w * w3.y;
            acc[r].z += hv.x * w0.z + hv.y * w1.z + hv.z * w2.z + hv.w * w3.z;
            acc[r].w += hv.x * w0.w + hv.y * w1.w + hv.z * w2.w + hv.w * w3.w;
        }
    }

    // store Wh as bf16 (RNE): row = 64 dwords; this thread owns uint2 slot (tid&31)
    #pragma unroll
    for (int r = 0; r < 8; ++r) {
        int gr = row0 + rg + r;
        if (gr < NNODES) {
            uint2 wv;
            wv.x = pack2bf(acc[r].x, acc[r].y);
            wv.y = pack2bf(acc[r].z, acc[r].w);
            ((uint2*)WhB)[(size_t)gr * 32 + (tid & 31)] = wv;
        }
    }

    // fused s1/s2 (from f32 accumulators — identical to reference's Wh @ a)
    float4 a1 = *(const float4*)&a[c4];
    float4 a2 = *(const float4*)&a[128 + c4];
    #pragma unroll
    for (int r = 0; r < 8; ++r) {
        float p1 = acc[r].x * a1.x + acc[r].y * a1.y + acc[r].z * a1.z + acc[r].w * a1.w;
        float p2 = acc[r].x * a2.x + acc[r].y * a2.y + acc[r].z * a2.z + acc[r].w * a2.w;
        #pragma unroll
        for (int off = 16; off; off >>= 1) {
            p1 += __shfl_xor(p1, off);
            p2 += __shfl_xor(p2, off);
        }
        int gr = row0 + rg + r;
        if ((tid & 31) == 0 && gr < NNODES) { s1[gr] = p1; s2[gr] = p2; }
    }
}

// ---------------------------------------------------------------------------
// K3a: per-chunk sums
// ---------------------------------------------------------------------------
__global__ __launch_bounds__(256) void chunk_sums(const int* __restrict__ count,
                                                  int* __restrict__ chunkSum) {
    __shared__ int red[256];
    int t = threadIdx.x;
    int idx = blockIdx.x * 256 + t;
    red[t] = (idx < NNODES) ? count[idx] : 0;
    __syncthreads();
    #pragma unroll
    for (int off = 128; off; off >>= 1) {
        if (t < off) red[t] += red[t + off];
        __syncthreads();
    }
    if (t == 0) chunkSum[blockIdx.x] = red[0];
}

// ---------------------------------------------------------------------------
// K3b: scan chunk sums (single 256-thread block)
// ---------------------------------------------------------------------------
__global__ __launch_bounds__(256) void scan_chunks(const int* __restrict__ chunkSum,
                                                   int* __restrict__ chunkBase,
                                                   int* __restrict__ rowstart) {
    __shared__ int s[256];
    int t = threadIdx.x;
    int v = (t < NBLK) ? chunkSum[t] : 0;
    s[t] = v;
    __syncthreads();
    #pragma unroll
    for (int off = 1; off < 256; off <<= 1) {
        int x = (t >= off) ? s[t - off] : 0;
        __syncthreads();
        s[t] += x;
        __syncthreads();
    }
    if (t < NBLK) chunkBase[t] = s[t] - v;
    if (t == 255) rowstart[NNODES] = s[255];
}

// ---------------------------------------------------------------------------
// K3c: local scan + chunk base -> rowstart
// ---------------------------------------------------------------------------
__global__ __launch_bounds__(256) void write_rowstart(const int* __restrict__ count,
                                                      const int* __restrict__ chunkBase,
                                                      int* __restrict__ rowstart) {
    __shared__ int s[256];
    int t = threadIdx.x;
    int idx = blockIdx.x * 256 + t;
    int v = (idx < NNODES) ? count[idx] : 0;
    s[t] = v;
    __syncthreads();
    #pragma unroll
    for (int off = 1; off < 256; off <<= 1) {
        int x = (t >= off) ? s[t - off] : 0;
        __syncthreads();
        s[t] += x;
        __syncthreads();
    }
    if (idx < NNODES) rowstart[idx] = chunkBase[blockIdx.x] + s[t] - v;
}

// ---------------------------------------------------------------------------
// K4: scatter pass — NO atomics: pos = rowstart[r] + rank[i]
//     pair[pos] = (leaky_relu(s1[r]+s2[c]), col)      [RAW e — exp happens later
//     against the row-sum shift, replicating reference EPS/underflow semantics]
// ---------------------------------------------------------------------------
__global__ __launch_bounds__(256) void scatter_edges(const int* __restrict__ ei,
                                                     const int* __restrict__ rank,
                                                     const int* __restrict__ rowstart,
                                                     const float* __restrict__ s1,
                                                     const float* __restrict__ s2,
                                                     float2* __restrict__ pair) {
    const int base = blockIdx.x * blockDim.x + threadIdx.x;
    const int stride = gridDim.x * blockDim.x;
    int idx[EPT], r[EPT], c[EPT], rk[EPT];
    #pragma unroll
    for (int k = 0; k < EPT; ++k) {
        idx[k] = base + k * stride;
        if (idx[k] < NEDGES) {
            r[k] = ei[idx[k]];
            c[k] = ei[NEDGES + idx[k]];
            rk[k] = rank[idx[k]];
        } else r[k] = -1;
    }
    float sv1[EPT], sv2[EPT];
    int rs[EPT];
    #pragma unroll
    for (int k = 0; k < EPT; ++k)
        if (r[k] >= 0) { sv1[k] = s1[r[k]]; sv2[k] = s2[c[k]]; rs[k] = rowstart[r[k]]; }
    #pragma unroll
    for (int k = 0; k < EPT; ++k)
        if (r[k] >= 0) {
            float s = sv1[k] + sv2[k];
            float ev = (s >= 0.f) ? s : ALPHA * s;
            pair[rs[k] + rk[k]] = make_float2(ev, __int_as_float(c[k]));
        }
}

// ---------------------------------------------------------------------------
// K5: per-row aggregation, one wave per row.
//   pass A1: rs = sum(e)                       (reference's rowsum shift)
//   pass A2: w_j = exp(e_j - rs) cached in LDS (deg<=128), dsum = sum(w)
//   pass B : acc += (w/(dsum+EPS)) * WhB[col]  (pure gather+FMA, x8 ILP)
//   deg>128 fallback: recompute exp in pass B (exact same arithmetic).
// ---------------------------------------------------------------------------
__global__ __launch_bounds__(256) void aggregate(const int* __restrict__ rowstart,
                                                 const float2* __restrict__ pair,
                                                 const unsigned* __restrict__ WhB,
                                                 float* __restrict__ out) {
    __shared__ float wsh[4][MAXDEG];
    const int wid = threadIdx.x >> 6;
    const int lane = threadIdx.x & 63;
    const int row = blockIdx.x * 4 + wid;
    if (row >= NNODES) return;
    const int start = rowstart[row];
    const int end = rowstart[row + 1];
    const int deg = end - start;

    // pass A1: row-sum of e (replicates reference rowsum)
    float esum = 0.f;
    for (int j = start + lane; j < end; j += 64) esum += pair[j].x;
    #pragma unroll
    for (int off = 32; off; off >>= 1) esum += __shfl_xor(esum, off);
    const float rs = esum;

    // pass A2: exp(e - rs), cache in LDS if it fits, accumulate denom
    float dsum = 0.f;
    const bool fits = (deg <= MAXDEG);
    if (fits) {
        for (int j = start + lane; j < end; j += 64) {
            float x = expf(pair[j].x - rs);
            wsh[wid][j - start] = x;
            dsum += x;
        }
    } else {
        for (int j = start + lane; j < end; j += 64) dsum += expf(pair[j].x - rs);
    }
    #pragma unroll
    for (int off = 32; off; off >>= 1) dsum += __shfl_xor(dsum, off);
    const float invd = 1.0f / (dsum + EPS);

    // pass B: weighted gather-accumulate, 8 gathers in flight
    float accx = 0.f, accy = 0.f;
    if (fits) {
        int j = start;
        for (; j + 8 <= end; j += 8) {
            int cs[8];
            #pragma unroll
            for (int k = 0; k < 8; ++k) cs[k] = __float_as_int(pair[j + k].y);
            unsigned u[8];
            #pragma unroll
            for (int k = 0; k < 8; ++k) u[k] = WhB[(size_t)cs[k] * 64 + lane];
            #pragma unroll
            for (int k = 0; k < 8; ++k) {
                float w = wsh[wid][j - start + k] * invd;
                accx += w * __uint_as_float(u[k] << 16);
                accy += w * __uint_as_float(u[k] & 0xFFFF0000u);
            }
        }
        for (; j < end; ++j) {
            int c = __float_as_int(pair[j].y);
            unsigned u = WhB[(size_t)c * 64 + lane];
            float w = wsh[wid][j - start] * invd;
            accx += w * __uint_as_float(u << 16);
            accy += w * __uint_as_float(u & 0xFFFF0000u);
        }
    } else {
        for (int j = start; j < end; ++j) {
            float2 p = pair[j];
            unsigned u = WhB[(size_t)__float_as_int(p.y) * 64 + lane];
            float w = expf(p.x - rs) * invd;
            accx += w * __uint_as_float(u << 16);
            accy += w * __uint_as_float(u & 0xFFFF0000u);
        }
    }
    // lane owns columns 2*lane, 2*lane+1
    ((float2*)out)[(size_t)row * 64 + lane] = make_float2(accx, accy);
}

// ---------------------------------------------------------------------------
extern "C" void kernel_launch(void* const* d_in, const int* in_sizes, int n_in,
                              void* d_out, int out_size, void* d_ws, size_t ws_size,
                              hipStream_t stream) {
    const float* h  = (const float*)d_in[0];
    const int*   ei = (const int*)d_in[1];
    const float* W  = (const float*)d_in[2];
    const float* a  = (const float*)d_in[3];
    float* out = (float*)d_out;

    char* ws = (char*)d_ws;
    size_t off = 0;
    auto alloc = [&](size_t bytes) -> void* {
        void* p = ws + off;
        off += (bytes + 255) & ~(size_t)255;
        return p;
    };

    unsigned* WhB      = (unsigned*)alloc((size_t)NNODES * 64 * 4);  // bf16 Wh, 64 dwords/row
    int*      count    = (int*)alloc((size_t)NNODES * 4);
    float*    s1       = (float*)alloc((size_t)NNODES * 4);
    float*    s2       = (float*)alloc((size_t)NNODES * 4);
    int*      rowstart = (int*)alloc((size_t)(NNODES + 1) * 4);
    int*      rank     = (int*)alloc((size_t)NEDGES * 4);
    float2*   pair     = (float2*)alloc((size_t)NEDGES * 8);
    int*      chunkSum = (int*)alloc((size_t)NBLK * 4);
    int*      chunkBase= (int*)alloc((size_t)NBLK * 4);

    hipMemsetAsync(count, 0, (size_t)NNODES * 4, stream);

    // K1: fused GEMM(bf16 out)+s1/s2  ||  histogram+rank
    gemm_count<<<GEMM_BLOCKS + CNT_BLOCKS, 256, 0, stream>>>(h, W, a, ei, WhB, s1, s2, count, rank);
    // K3: hierarchical scan
    chunk_sums<<<NBLK, 256, 0, stream>>>(count, chunkSum);
    scan_chunks<<<1, 256, 0, stream>>>(chunkSum, chunkBase, rowstart);
    write_rowstart<<<NBLK, 256, 0, stream>>>(count, chunkBase, rowstart);
    // K4: atomic-free scatter, stores raw e
    scatter_edges<<<CNT_BLOCKS, 256, 0, stream>>>(ei, rank, rowstart, s1, s2, pair);
    // K5: aggregate (exp vs row-sum shift, LDS-cached weights, bf16 gather)
    aggregate<<<(NNODES + 3) / 4, 256, 0, stream>>>(rowstart, pair, WhB, out);
}